// Round 3
// baseline (555.248 us; speedup 1.0000x reference)
//
#include <hip/hip_runtime.h>

// IndRNN: h_t = relu(x_t + w * h_{t-1}), w >= 0 (U(0,1)).
// R4: single-kernel chunked scan with decoupled lookback.
//  - Evidence from R0-R3 rocprof: every kernel < 163 us (none crack the
//    top-5 fills) => dur_us = sum(kernels) + ~258 us fixed harness cost.
//    So minimize launches AND total traffic.
//  - Step composes in F(h) = max(m, a + b*h) for w>=0 (verified R2/R3).
//  - One launch: block (chunk c, group g) computes local (m,a) from its
//    256 KB x-slice, publishes with agent-scope release + flag, acquires
//    <=31 predecessor flags, composes h_start in-register, replays its
//    slice (x re-read hits L3: MALL is memory-side, survives acquire inv)
//    and writes out. Traffic ~530 MB vs 790 MB (R2/R3) vs 537 MB (R0).
//  - Deadlock-free: __launch_bounds__(256,4) => 4 blocks/CU => all 1024
//    blocks co-resident; flags zeroed by a tiny prologue kernel (ws is
//    poisoned by the harness, cannot assume zero).

#define T_STEPS 2048
#define B_DIM   32
#define H_DIM   1024
#define BH      (B_DIM * H_DIM)      // 32768 channels
#define BH4     (BH / 4)             // 8192 float4 quads per time row
#define NCHUNK  32                   // chunks along T
#define CLEN    (T_STEPS / NCHUNK)   // 64 steps per chunk
#define GRPS    (BH4 / 256)          // 32 channel-groups (blocks per chunk)
#define PF      8                    // prefetch depth (time steps)

typedef float f4 __attribute__((ext_vector_type(4)));

__device__ __forceinline__ f4 step_relu(const f4 w, const f4 h, const f4 x) {
    f4 r;
    r.x = fmaxf(fmaf(w.x, h.x, x.x), 0.f);
    r.y = fmaxf(fmaf(w.y, h.y, x.y), 0.f);
    r.z = fmaxf(fmaf(w.z, h.z, x.z), 0.f);
    r.w = fmaxf(fmaf(w.w, h.w, x.w), 0.f);
    return r;
}

__device__ __forceinline__ f4 step_lin(const f4 w, const f4 a, const f4 x) {
    f4 r;
    r.x = fmaf(w.x, a.x, x.x);
    r.y = fmaf(w.y, a.y, x.y);
    r.z = fmaf(w.z, a.z, x.z);
    r.w = fmaf(w.w, a.w, x.w);
    return r;
}

__global__ void zero_flags(unsigned* __restrict__ f) {
    f[blockIdx.x * 256 + threadIdx.x] = 0u;
}

__global__ __launch_bounds__(256, 4)
void indrnn_lookback(const f4* __restrict__ x, const f4* __restrict__ h0,
                     const f4* __restrict__ w, f4* __restrict__ out,
                     f4* __restrict__ m_ws, f4* __restrict__ a_ws,
                     unsigned* __restrict__ flags)
{
    const int bid = blockIdx.x;
    const int c   = bid >> 5;            // chunk id (slow axis: ascending dispatch)
    const int g   = bid & 31;            // channel group
    const int tid = threadIdx.x;
    const int q   = (g << 8) + tid;      // quad id 0..BH4-1; q % 256 == tid

    const f4 wv = w[tid];                // per-H weight quad

    f4 b4 = wv;                          // b4 = w^64 via 6 squarings
#pragma unroll
    for (int i = 0; i < 6; ++i) {
        b4.x *= b4.x; b4.y *= b4.y; b4.z *= b4.z; b4.w *= b4.w;
    }

    const f4* xp = x + (size_t)c * CLEN * BH4 + q;

    f4 m, a, h0v;
    a.x = a.y = a.z = a.w = 0.f;
    if (c == 0) { h0v = h0[q]; m = h0v; }        // chunk 0: track exact value
    else        { m.x = m.y = m.z = m.w = 0.f; } // identity start (h>=0 upstream)

    // ---------------- phase A: local composed function (m, a) ----------------
    f4 buf[PF];
#pragma unroll
    for (int i = 0; i < PF; ++i) buf[i] = xp[(size_t)i * BH4];

    int t0 = 0;
    for (; t0 + PF < CLEN; t0 += PF) {
        f4 nxt[PF];
#pragma unroll
        for (int i = 0; i < PF; ++i) nxt[i] = xp[(size_t)(t0 + PF + i) * BH4];
#pragma unroll
        for (int i = 0; i < PF; ++i) {
            m = step_relu(wv, m, buf[i]);
            a = step_lin(wv, a, buf[i]);
        }
#pragma unroll
        for (int i = 0; i < PF; ++i) buf[i] = nxt[i];
    }
#pragma unroll
    for (int i = 0; i < PF; ++i) {
        m = step_relu(wv, m, buf[i]);
        a = step_lin(wv, a, buf[i]);
    }

    // publish (m, a); __syncthreads drains each wave's vmcnt before barrier,
    // release store then flushes XCD L2 -> coherence point before flag set.
    m_ws[(size_t)c * BH4 + q] = m;
    a_ws[(size_t)c * BH4 + q] = a;
    __syncthreads();
    if (tid == 0)
        __hip_atomic_store(&flags[bid], 1u, __ATOMIC_RELEASE,
                           __HIP_MEMORY_SCOPE_AGENT);

    // ---------------- lookback: h_start for this chunk ----------------
    f4 v;
    if (c == 0) {
        v = h0v;
    } else {
        if (tid < c) {                   // thread j spins on chunk j's flag
            const unsigned* fp = &flags[(tid << 5) | g];
            while (__hip_atomic_load(fp, __ATOMIC_ACQUIRE,
                                     __HIP_MEMORY_SCOPE_AGENT) == 0u)
                __builtin_amdgcn_s_sleep(1);
        }
        __syncthreads();                 // acquires invalidated CU L1 + XCD L2

        const f4* mp = m_ws + q;
        const f4* ap = a_ws + q;
        v = mp[0];                       // exact h after chunk 0 (h0-seeded)
#pragma unroll 4
        for (int j = 1; j < c; ++j) {
            const f4 mj = mp[(size_t)j * BH4];
            const f4 aj = ap[(size_t)j * BH4];
            v.x = fmaxf(fmaf(b4.x, v.x, aj.x), mj.x);
            v.y = fmaxf(fmaf(b4.y, v.y, aj.y), mj.y);
            v.z = fmaxf(fmaf(b4.z, v.z, aj.z), mj.z);
            v.w = fmaxf(fmaf(b4.w, v.w, aj.w), mj.w);
        }
    }

    // ---------------- phase C: replay exact recurrence, write out ----------------
    f4 h = v;
    f4* op = out + (size_t)c * CLEN * BH4 + q;

#pragma unroll
    for (int i = 0; i < PF; ++i) buf[i] = xp[(size_t)i * BH4];

    t0 = 0;
    for (; t0 + PF < CLEN; t0 += PF) {
        f4 nxt[PF];
#pragma unroll
        for (int i = 0; i < PF; ++i) nxt[i] = xp[(size_t)(t0 + PF + i) * BH4];
#pragma unroll
        for (int i = 0; i < PF; ++i) {
            h = step_relu(wv, h, buf[i]);
            op[(size_t)(t0 + i) * BH4] = h;
        }
#pragma unroll
        for (int i = 0; i < PF; ++i) buf[i] = nxt[i];
    }
#pragma unroll
    for (int i = 0; i < PF; ++i) {
        h = step_relu(wv, h, buf[i]);
        op[(size_t)(t0 + i) * BH4] = h;
    }
}

extern "C" void kernel_launch(void* const* d_in, const int* in_sizes, int n_in,
                              void* d_out, int out_size, void* d_ws, size_t ws_size,
                              hipStream_t stream) {
    const f4* x  = (const f4*)d_in[0];  // (T, B, H)
    const f4* h0 = (const f4*)d_in[1];  // (B, H)
    const f4* w  = (const f4*)d_in[2];  // (H,)
    f4* out = (f4*)d_out;               // (T, B, H)

    // workspace: m (4 MB) | a (4 MB) | flags (4 KB)
    float* m = (float*)d_ws;
    float* a = m + (size_t)NCHUNK * BH;
    unsigned* flags = (unsigned*)(a + (size_t)NCHUNK * BH);

    zero_flags<<<(NCHUNK * GRPS) / 256, 256, 0, stream>>>(flags);
    indrnn_lookback<<<NCHUNK * GRPS, 256, 0, stream>>>(
        x, h0, w, out, (f4*)m, (f4*)a, flags);
}